// Round 2
// baseline (695.572 us; speedup 1.0000x reference)
//
#include <hip/hip_runtime.h>
#include <stdint.h>

// Problem constants
#define T_    256
#define B_    4
#define U_    64
#define EENC  1024
#define EDEC  640
#define J_    640
#define V_    4096

typedef unsigned short u16;
typedef unsigned int   u32;
typedef __bf16 bf16x8 __attribute__((ext_vector_type(8)));
typedef short  s16x8  __attribute__((ext_vector_type(8)));
typedef float  f32x4  __attribute__((ext_vector_type(4)));

__device__ __forceinline__ u16 f2bf(float f) {
    u32 u = __builtin_bit_cast(u32, f);
    u = (u + 0x7FFFu + ((u >> 16) & 1u)) >> 16;
    return (u16)u;
}
__device__ __forceinline__ float bf2f(u16 b) {
    return __builtin_bit_cast(float, (u32)b << 16);
}

// ---------------- f32 -> bf16 convert (vectorized x4) ----------------
__global__ __launch_bounds__(256) void cvt_bf16(const float* __restrict__ src,
                                                u16* __restrict__ dst, int n4) {
    int i = blockIdx.x * 256 + threadIdx.x;
    if (i < n4) {
        float4 v = reinterpret_cast<const float4*>(src)[i];
        ushort4 o;
        o.x = f2bf(v.x); o.y = f2bf(v.y); o.z = f2bf(v.z); o.w = f2bf(v.w);
        reinterpret_cast<ushort4*>(dst)[i] = o;
    }
}

// ---------------- LayerNorm over J=640 + bias + affine, bf16 out, transposed ----------------
__global__ __launch_bounds__(256) void ln_kernel(const float* __restrict__ proj,
                                                 const float* __restrict__ bias,
                                                 const float* __restrict__ gamma,
                                                 const float* __restrict__ beta,
                                                 u16* __restrict__ out,
                                                 int BDIM, int OUTER) {
    int pr = blockIdx.x;
    int b = pr % BDIM, outer = pr / BDIM;
    const float* row = proj + (size_t)pr * J_;
    int tid = threadIdx.x;

    float x0 = row[tid] + bias[tid];
    float x1 = row[tid + 256] + bias[tid + 256];
    float x2 = 0.f;
    bool has3 = (tid < J_ - 512);
    if (has3) x2 = row[tid + 512] + bias[tid + 512];

    float s1 = x0 + x1 + x2;
    float s2 = x0 * x0 + x1 * x1 + x2 * x2;
    for (int off = 32; off; off >>= 1) {
        s1 += __shfl_down(s1, off, 64);
        s2 += __shfl_down(s2, off, 64);
    }
    __shared__ float ws1[4], ws2[4];
    int w = tid >> 6, lane = tid & 63;
    if (lane == 0) { ws1[w] = s1; ws2[w] = s2; }
    __syncthreads();
    float S1 = ws1[0] + ws1[1] + ws1[2] + ws1[3];
    float S2 = ws2[0] + ws2[1] + ws2[2] + ws2[3];
    float mu = S1 * (1.f / J_);
    float var = S2 * (1.f / J_) - mu * mu;
    float inv = 1.0f / sqrtf(var + 1e-5f);

    size_t orow = ((size_t)b * OUTER + outer) * J_;
    out[orow + tid]       = f2bf((x0 - mu) * inv * gamma[tid]       + beta[tid]);
    out[orow + tid + 256] = f2bf((x1 - mu) * inv * gamma[tid + 256] + beta[tid + 256]);
    if (has3)
        out[orow + tid + 512] = f2bf((x2 - mu) * inv * gamma[tid + 512] + beta[tid + 512]);
}

// ---------------- joint materialization: relu(enc[b,t,:] + dec[b,u,:]) -> bf16 [B*T*U][J] ----------------
__global__ __launch_bounds__(256) void joint_mat(const u16* __restrict__ encln,
                                                 const u16* __restrict__ decln,
                                                 u16* __restrict__ joint) {
    int g = blockIdx.x * 256 + threadIdx.x;
    int row = g / (J_ / 8);
    int jc = g - row * (J_ / 8);
    int b = row >> 14;
    int t = (row >> 6) & (T_ - 1);
    int u = row & (U_ - 1);
    s16x8 e = *reinterpret_cast<const s16x8*>(encln + ((size_t)(b * T_ + t)) * J_ + jc * 8);
    s16x8 d = *reinterpret_cast<const s16x8*>(decln + ((size_t)(b * U_ + u)) * J_ + jc * 8);
    s16x8 o;
#pragma unroll
    for (int k = 0; k < 8; ++k) {
        float v = bf2f((u16)e[k]) + bf2f((u16)d[k]);
        o[k] = (short)f2bf(fmaxf(v, 0.f));
    }
    *reinterpret_cast<s16x8*>(joint + (size_t)row * J_ + jc * 8) = o;
}

// ---------------- m97-structure 128x128 GEMM (stage-1 projections; J=640 not 256-divisible) ----------------
__global__ __launch_bounds__(256) void gemm_bt(const u16* __restrict__ A,
                                               const u16* __restrict__ Bt,
                                               float* __restrict__ C,
                                               const float* __restrict__ bias,
                                               int K, int ldc) {
    __shared__ u16 As[128 * 64];
    __shared__ u16 Bs[128 * 64];
    const int tid = threadIdx.x;
    const int w = tid >> 6, lane = tid & 63;
    const int wr = w >> 1, wc = w & 1;
    const size_t m0 = (size_t)blockIdx.y * 128;
    const size_t n0 = (size_t)blockIdx.x * 128;

    f32x4 acc[4][4] = {};

    const int l3 = lane >> 3;
    const int c8 = (lane & 7) * 8;
    const int nkt = K >> 6;

    for (int kt = 0; kt < nkt; ++kt) {
        if (kt) __syncthreads();
        const int k0 = kt << 6;
#pragma unroll
        for (int i = 0; i < 4; ++i) {
            const int c = w * 4 + i;
            const int r = c * 8 + l3;
            const u16* ga = A  + (m0 + r) * (size_t)K + k0 + c8;
            const u16* gb = Bt + (n0 + r) * (size_t)K + k0 + c8;
            __builtin_amdgcn_global_load_lds(
                (const __attribute__((address_space(1))) void*)ga,
                (__attribute__((address_space(3))) void*)(As + c * 512), 16, 0, 0);
            __builtin_amdgcn_global_load_lds(
                (const __attribute__((address_space(1))) void*)gb,
                (__attribute__((address_space(3))) void*)(Bs + c * 512), 16, 0, 0);
        }
        __syncthreads();

#pragma unroll
        for (int kk = 0; kk < 2; ++kk) {
            bf16x8 af[4], bfr[4];
#pragma unroll
            for (int i = 0; i < 4; ++i) {
                int ra = wr * 64 + i * 16 + (lane & 15);
                af[i] = *reinterpret_cast<const bf16x8*>(As + ra * 64 + kk * 32 + (lane >> 4) * 8);
                int rb = wc * 64 + i * 16 + (lane & 15);
                bfr[i] = *reinterpret_cast<const bf16x8*>(Bs + rb * 64 + kk * 32 + (lane >> 4) * 8);
            }
#pragma unroll
            for (int i = 0; i < 4; ++i)
#pragma unroll
                for (int j = 0; j < 4; ++j)
                    acc[i][j] = __builtin_amdgcn_mfma_f32_16x16x32_bf16(af[i], bfr[j], acc[i][j], 0, 0, 0);
        }
    }

    const int r4 = (lane >> 4) * 4;
    const int cl = lane & 15;
#pragma unroll
    for (int i = 0; i < 4; ++i) {
#pragma unroll
        for (int j = 0; j < 4; ++j) {
            size_t grow = m0 + wr * 64 + i * 16 + r4;
            size_t gcol = n0 + wc * 64 + j * 16 + cl;
            float bv = bias ? bias[gcol] : 0.f;
#pragma unroll
            for (int r = 0; r < 4; ++r)
                C[(grow + r) * (size_t)ldc + gcol] = acc[i][j][r] + bv;
        }
    }
}

// ---------------- 256x256 8-phase bf16 GEMM for the vocab projection ----------------
// M=65536, N=4096, K=640 fixed. 512 threads = 8 waves (2Mx4N), per-wave 128x64 out.
// T2 LDS XOR-swizzle (linear gload_lds dest + pre-swizzled global src + swizzled ds_read),
// T3/T4 phase schedule with vmcnt drained once per K-tile only, T5 setprio, T1 XCD swizzle.
#define BK   64
#define BIGK 640
#define BIGN 4096
#define NT_  (BIGK / BK)

__global__ __launch_bounds__(512, 2) void gemm_big(const u16* __restrict__ A,
                                                   const u16* __restrict__ Bt,
                                                   float* __restrict__ C,
                                                   const float* __restrict__ bias) {
    __shared__ u16 lds[2][2][256 * BK];   // [buf][0=A,1=B][row*64 + col]; 128 KiB

    const int tid = threadIdx.x;
    const int w = tid >> 6, lane = tid & 63;
    const int wr = w >> 2, wc = w & 3;
    const int fr = lane & 15, fq = lane >> 4;

    // T1: bijective XCD swizzle (nwg=4096, 8 XCDs, 512 wgs each)
    const int lin = blockIdx.x;
    const int swz = (lin & 7) * 512 + (lin >> 3);
    const size_t m0 = (size_t)(swz >> 4) * 256;
    const size_t n0 = (size_t)(swz & 15) * 256;

    // staging: call c stages rows [c*64, c*64+64) of one operand; wave w owns rows c*64+w*8..+7.
    // LDS dest is linear; global source column is pre-swizzled: colbyte = (l&7)*16 ^ ((l>>3)<<4)
    const int srow = lane >> 3;
    const int scol = ((lane & 7) * 16) ^ (srow << 4);      // byte offset within 128B k-chunk
    const u16* agbase = A  + (m0 + w * 8 + srow) * (size_t)BIGK + (scol >> 1);
    const u16* bgbase = Bt + (n0 + w * 8 + srow) * (size_t)BIGK + (scol >> 1);
    const int ldst = (w * 8) * BK;                          // u16 offset of wave's stripe in call 0

    f32x4 acc[8][4] = {};

#define STAGE_A(buf, c, k0)                                                        \
    __builtin_amdgcn_global_load_lds(                                              \
        (const __attribute__((address_space(1))) void*)(agbase + (size_t)(c) * 64 * BIGK + (k0)), \
        (__attribute__((address_space(3))) void*)(&lds[buf][0][(c) * 64 * BK + ldst]), 16, 0, 0)
#define STAGE_B(buf, c, k0)                                                        \
    __builtin_amdgcn_global_load_lds(                                              \
        (const __attribute__((address_space(1))) void*)(bgbase + (size_t)(c) * 64 * BIGK + (k0)), \
        (__attribute__((address_space(3))) void*)(&lds[buf][1][(c) * 64 * BK + ldst]), 16, 0, 0)

    // ds_read address: logical (row, colbyte=kk*64+fq*16) -> physical colbyte XOR ((row&7)<<4)
#define RD_A(buf, mh, mi, kk)                                                      \
    (*reinterpret_cast<const bf16x8*>(&lds[buf][0][                                \
        (wr * 128 + (mh) * 64 + (mi) * 16 + fr) * BK +                             \
        ((((kk) * 64 + fq * 16) ^ ((fr & 7) << 4)) >> 1)]))
#define RD_B(buf, ni, kk)                                                          \
    (*reinterpret_cast<const bf16x8*>(&lds[buf][1][                                \
        (wc * 64 + (ni) * 16 + fr) * BK +                                          \
        ((((kk) * 64 + fq * 16) ^ ((fr & 7) << 4)) >> 1)]))

    // prologue: stage tile 0 into buf 0, drain, barrier
#pragma unroll
    for (int c = 0; c < 4; ++c) { STAGE_A(0, c, 0); STAGE_B(0, c, 0); }
    asm volatile("s_waitcnt vmcnt(0)" ::: "memory");
    __builtin_amdgcn_s_barrier();

    for (int t = 0; t < NT_; ++t) {
        const int cur = t & 1, nxt = cur ^ 1;
        const int kn = (t + 1) << 6;
        const bool pf = (t + 1 < NT_);
        bf16x8 af[4], b0[4], b1[4];

        // ---- phase 0: kk=0, m-low ----
#pragma unroll
        for (int i = 0; i < 4; ++i) af[i] = RD_A(cur, 0, i, 0);
#pragma unroll
        for (int j = 0; j < 4; ++j) b0[j] = RD_B(cur, j, 0);
        if (pf) { STAGE_A(nxt, 0, kn); STAGE_B(nxt, 0, kn); STAGE_A(nxt, 1, kn); STAGE_B(nxt, 1, kn); }
        __builtin_amdgcn_s_barrier();
        asm volatile("s_waitcnt lgkmcnt(0)" ::: "memory");
        __builtin_amdgcn_s_setprio(1);
#pragma unroll
        for (int i = 0; i < 4; ++i)
#pragma unroll
            for (int j = 0; j < 4; ++j)
                acc[i][j] = __builtin_amdgcn_mfma_f32_16x16x32_bf16(af[i], b0[j], acc[i][j], 0, 0, 0);
        __builtin_amdgcn_s_setprio(0);
        __builtin_amdgcn_s_barrier();

        // ---- phase 1: kk=0, m-high ----
#pragma unroll
        for (int i = 0; i < 4; ++i) af[i] = RD_A(cur, 1, i, 0);
        if (pf) { STAGE_A(nxt, 2, kn); STAGE_B(nxt, 2, kn); STAGE_A(nxt, 3, kn); STAGE_B(nxt, 3, kn); }
        __builtin_amdgcn_s_barrier();
        asm volatile("s_waitcnt lgkmcnt(0)" ::: "memory");
        __builtin_amdgcn_s_setprio(1);
#pragma unroll
        for (int i = 0; i < 4; ++i)
#pragma unroll
            for (int j = 0; j < 4; ++j)
                acc[4 + i][j] = __builtin_amdgcn_mfma_f32_16x16x32_bf16(af[i], b0[j], acc[4 + i][j], 0, 0, 0);
        __builtin_amdgcn_s_setprio(0);
        __builtin_amdgcn_s_barrier();

        // ---- phase 2: kk=1, m-low ----
#pragma unroll
        for (int i = 0; i < 4; ++i) af[i] = RD_A(cur, 0, i, 1);
#pragma unroll
        for (int j = 0; j < 4; ++j) b1[j] = RD_B(cur, j, 1);
        __builtin_amdgcn_s_barrier();
        asm volatile("s_waitcnt lgkmcnt(0)" ::: "memory");
        __builtin_amdgcn_s_setprio(1);
#pragma unroll
        for (int i = 0; i < 4; ++i)
#pragma unroll
            for (int j = 0; j < 4; ++j)
                acc[i][j] = __builtin_amdgcn_mfma_f32_16x16x32_bf16(af[i], b1[j], acc[i][j], 0, 0, 0);
        __builtin_amdgcn_s_setprio(0);
        __builtin_amdgcn_s_barrier();

        // ---- phase 3: kk=1, m-high ----
#pragma unroll
        for (int i = 0; i < 4; ++i) af[i] = RD_A(cur, 1, i, 1);
        __builtin_amdgcn_s_barrier();
        asm volatile("s_waitcnt lgkmcnt(0)" ::: "memory");
        __builtin_amdgcn_s_setprio(1);
#pragma unroll
        for (int i = 0; i < 4; ++i)
#pragma unroll
            for (int j = 0; j < 4; ++j)
                acc[4 + i][j] = __builtin_amdgcn_mfma_f32_16x16x32_bf16(af[i], b1[j], acc[4 + i][j], 0, 0, 0);
        __builtin_amdgcn_s_setprio(0);
        // tile boundary: next tile's data must be resident before phase 0 ds_reads.
        // per-wave drain of its own stage loads, then barrier covers all waves.
        asm volatile("s_waitcnt vmcnt(0)" ::: "memory");
        __builtin_amdgcn_s_barrier();
    }

#undef STAGE_A
#undef STAGE_B
#undef RD_A
#undef RD_B

    // epilogue: C[row=(lane>>4)*4+r, col=lane&15] per 16x16 fragment, + bias
    const size_t crow0 = m0 + wr * 128 + fq * 4;
    const size_t ccol0 = n0 + wc * 64 + fr;
#pragma unroll
    for (int ni = 0; ni < 4; ++ni) {
        const size_t col = ccol0 + ni * 16;
        const float bv = bias[col];
#pragma unroll
        for (int mi = 0; mi < 8; ++mi) {
            const size_t rbase = crow0 + mi * 16;
#pragma unroll
            for (int r = 0; r < 4; ++r)
                C[(rbase + r) * (size_t)BIGN + col] = acc[mi][ni][r] + bv;
        }
    }
}

// ---------------- workspace layout (bytes) ----------------
static const size_t O_JOINT = 0;                              // bf16 [65536][640]
static const size_t O_WOUT  = 83886080;                       // bf16 [4096][640]
static const size_t O_ENCLN = 89128960;                       // bf16 [B*T][J]
static const size_t O_DECLN = 90439680;                       // bf16 [B*U][J]
static const size_t O_ENCIN = 90767360;                       // bf16 [T*B][EENC]
static const size_t O_DECIN = 92864512;                       // bf16 [U*B][EDEC]
static const size_t O_WENC  = 93192192;                       // bf16 [J][EENC]
static const size_t O_WDEC  = 94502912;                       // bf16 [J][EDEC]
static const size_t O_EPROJ = 95322112;                       // f32  [T*B][J]
static const size_t O_DPROJ = 97943552;                       // f32  [U*B][J]
static const size_t WS_NEEDED = 98598912;

extern "C" void kernel_launch(void* const* d_in, const int* in_sizes, int n_in,
                              void* d_out, int out_size, void* d_ws, size_t ws_size,
                              hipStream_t stream) {
    const float* enc   = (const float*)d_in[0];
    const float* dec   = (const float*)d_in[1];
    const float* Wenc  = (const float*)d_in[2];
    const float* benc  = (const float*)d_in[3];
    const float* genc  = (const float*)d_in[4];
    const float* beenc = (const float*)d_in[5];
    const float* Wdec  = (const float*)d_in[6];
    const float* bdec  = (const float*)d_in[7];
    const float* gdec  = (const float*)d_in[8];
    const float* bedec = (const float*)d_in[9];
    const float* Wout  = (const float*)d_in[10];
    const float* bout  = (const float*)d_in[11];
    float* out = (float*)d_out;

    if (ws_size < WS_NEEDED) return;

    char* ws = (char*)d_ws;
    u16* joint  = (u16*)(ws + O_JOINT);
    u16* wout_b = (u16*)(ws + O_WOUT);
    u16* encln  = (u16*)(ws + O_ENCLN);
    u16* decln  = (u16*)(ws + O_DECLN);
    u16* encin  = (u16*)(ws + O_ENCIN);
    u16* decin  = (u16*)(ws + O_DECIN);
    u16* wenc_b = (u16*)(ws + O_WENC);
    u16* wdec_b = (u16*)(ws + O_WDEC);
    float* eproj = (float*)(ws + O_EPROJ);
    float* dproj = (float*)(ws + O_DPROJ);

    // 1) bf16 converts
    cvt_bf16<<<1024, 256, 0, stream>>>(enc,  encin,  (T_ * B_ * EENC) / 4);
    cvt_bf16<<<160,  256, 0, stream>>>(dec,  decin,  (U_ * B_ * EDEC) / 4);
    cvt_bf16<<<640,  256, 0, stream>>>(Wenc, wenc_b, (J_ * EENC) / 4);
    cvt_bf16<<<400,  256, 0, stream>>>(Wdec, wdec_b, (J_ * EDEC) / 4);
    cvt_bf16<<<2560, 256, 0, stream>>>(Wout, wout_b, (V_ * J_) / 4);

    // 2) stage-1 projections (bias folded into LN)
    gemm_bt<<<dim3(J_ / 128, (T_ * B_) / 128), 256, 0, stream>>>(encin, wenc_b, eproj, nullptr, EENC, J_);
    gemm_bt<<<dim3(J_ / 128, (U_ * B_) / 128), 256, 0, stream>>>(decin, wdec_b, dproj, nullptr, EDEC, J_);

    // 3) LayerNorm (+bias +affine), transpose to [B, T/U, J], bf16
    ln_kernel<<<T_ * B_, 256, 0, stream>>>(eproj, benc, genc, beenc, encln, B_, T_);
    ln_kernel<<<U_ * B_, 256, 0, stream>>>(dproj, bdec, gdec, bedec, decln, B_, U_);

    // 4) joint = relu(enc + dec) materialized bf16 [B*T*U][J]
    joint_mat<<<(B_ * T_ * U_ * (J_ / 8)) / 256, 256, 0, stream>>>(encln, decln, joint);

    // 5) vocab projection: [65536, 640] x [640, 4096]^T + b_out -> d_out (8-phase 256^2)
    gemm_big<<<(B_ * T_ * U_ / 256) * (V_ / 256), 512, 0, stream>>>(joint, wout_b, out, bout);
}

// Round 3
// 533.577 us; speedup vs baseline: 1.3036x; 1.3036x over previous
//
#include <hip/hip_runtime.h>
#include <stdint.h>

// Problem constants
#define T_    256
#define B_    4
#define U_    64
#define EENC  1024
#define EDEC  640
#define J_    640
#define V_    4096

typedef unsigned short u16;
typedef unsigned int   u32;
typedef __bf16 bf16x8 __attribute__((ext_vector_type(8)));
typedef short  s16x8  __attribute__((ext_vector_type(8)));
typedef float  f32x4  __attribute__((ext_vector_type(4)));

__device__ __forceinline__ u16 f2bf(float f) {
    u32 u = __builtin_bit_cast(u32, f);
    u = (u + 0x7FFFu + ((u >> 16) & 1u)) >> 16;
    return (u16)u;
}
__device__ __forceinline__ float bf2f(u16 b) {
    return __builtin_bit_cast(float, (u32)b << 16);
}

// ---------------- f32 -> bf16 convert (vectorized x4) ----------------
__global__ __launch_bounds__(256) void cvt_bf16(const float* __restrict__ src,
                                                u16* __restrict__ dst, int n4) {
    int i = blockIdx.x * 256 + threadIdx.x;
    if (i < n4) {
        float4 v = reinterpret_cast<const float4*>(src)[i];
        ushort4 o;
        o.x = f2bf(v.x); o.y = f2bf(v.y); o.z = f2bf(v.z); o.w = f2bf(v.w);
        reinterpret_cast<ushort4*>(dst)[i] = o;
    }
}

// ---------------- LayerNorm over J=640 + bias + affine, bf16 out, transposed ----------------
__global__ __launch_bounds__(256) void ln_kernel(const float* __restrict__ proj,
                                                 const float* __restrict__ bias,
                                                 const float* __restrict__ gamma,
                                                 const float* __restrict__ beta,
                                                 u16* __restrict__ out,
                                                 int BDIM, int OUTER) {
    int pr = blockIdx.x;
    int b = pr % BDIM, outer = pr / BDIM;
    const float* row = proj + (size_t)pr * J_;
    int tid = threadIdx.x;

    float x0 = row[tid] + bias[tid];
    float x1 = row[tid + 256] + bias[tid + 256];
    float x2 = 0.f;
    bool has3 = (tid < J_ - 512);
    if (has3) x2 = row[tid + 512] + bias[tid + 512];

    float s1 = x0 + x1 + x2;
    float s2 = x0 * x0 + x1 * x1 + x2 * x2;
    for (int off = 32; off; off >>= 1) {
        s1 += __shfl_down(s1, off, 64);
        s2 += __shfl_down(s2, off, 64);
    }
    __shared__ float ws1[4], ws2[4];
    int w = tid >> 6, lane = tid & 63;
    if (lane == 0) { ws1[w] = s1; ws2[w] = s2; }
    __syncthreads();
    float S1 = ws1[0] + ws1[1] + ws1[2] + ws1[3];
    float S2 = ws2[0] + ws2[1] + ws2[2] + ws2[3];
    float mu = S1 * (1.f / J_);
    float var = S2 * (1.f / J_) - mu * mu;
    float inv = 1.0f / sqrtf(var + 1e-5f);

    size_t orow = ((size_t)b * OUTER + outer) * J_;
    out[orow + tid]       = f2bf((x0 - mu) * inv * gamma[tid]       + beta[tid]);
    out[orow + tid + 256] = f2bf((x1 - mu) * inv * gamma[tid + 256] + beta[tid + 256]);
    if (has3)
        out[orow + tid + 512] = f2bf((x2 - mu) * inv * gamma[tid + 512] + beta[tid + 512]);
}

// ---------------- joint materialization: relu(enc[b,t,:] + dec[b,u,:]) -> bf16 [B*T*U][J] ----------------
__global__ __launch_bounds__(256) void joint_mat(const u16* __restrict__ encln,
                                                 const u16* __restrict__ decln,
                                                 u16* __restrict__ joint) {
    int g = blockIdx.x * 256 + threadIdx.x;
    int row = g / (J_ / 8);
    int jc = g - row * (J_ / 8);
    int b = row >> 14;
    int t = (row >> 6) & (T_ - 1);
    int u = row & (U_ - 1);
    s16x8 e = *reinterpret_cast<const s16x8*>(encln + ((size_t)(b * T_ + t)) * J_ + jc * 8);
    s16x8 d = *reinterpret_cast<const s16x8*>(decln + ((size_t)(b * U_ + u)) * J_ + jc * 8);
    s16x8 o;
#pragma unroll
    for (int k = 0; k < 8; ++k) {
        float v = bf2f((u16)e[k]) + bf2f((u16)d[k]);
        o[k] = (short)f2bf(fmaxf(v, 0.f));
    }
    *reinterpret_cast<s16x8*>(joint + (size_t)row * J_ + jc * 8) = o;
}

// ---------------- m97-structure 128x128 GEMM (stage-1 projections) ----------------
__global__ __launch_bounds__(256) void gemm_bt(const u16* __restrict__ A,
                                               const u16* __restrict__ Bt,
                                               float* __restrict__ C,
                                               const float* __restrict__ bias,
                                               int K, int ldc) {
    __shared__ u16 As[128 * 64];
    __shared__ u16 Bs[128 * 64];
    const int tid = threadIdx.x;
    const int w = tid >> 6, lane = tid & 63;
    const int wr = w >> 1, wc = w & 1;
    const size_t m0 = (size_t)blockIdx.y * 128;
    const size_t n0 = (size_t)blockIdx.x * 128;

    f32x4 acc[4][4] = {};

    const int l3 = lane >> 3;
    const int c8 = (lane & 7) * 8;
    const int nkt = K >> 6;

    for (int kt = 0; kt < nkt; ++kt) {
        if (kt) __syncthreads();
        const int k0 = kt << 6;
#pragma unroll
        for (int i = 0; i < 4; ++i) {
            const int c = w * 4 + i;
            const int r = c * 8 + l3;
            const u16* ga = A  + (m0 + r) * (size_t)K + k0 + c8;
            const u16* gb = Bt + (n0 + r) * (size_t)K + k0 + c8;
            __builtin_amdgcn_global_load_lds(
                (const __attribute__((address_space(1))) void*)ga,
                (__attribute__((address_space(3))) void*)(As + c * 512), 16, 0, 0);
            __builtin_amdgcn_global_load_lds(
                (const __attribute__((address_space(1))) void*)gb,
                (__attribute__((address_space(3))) void*)(Bs + c * 512), 16, 0, 0);
        }
        __syncthreads();

#pragma unroll
        for (int kk = 0; kk < 2; ++kk) {
            bf16x8 af[4], bfr[4];
#pragma unroll
            for (int i = 0; i < 4; ++i) {
                int ra = wr * 64 + i * 16 + (lane & 15);
                af[i] = *reinterpret_cast<const bf16x8*>(As + ra * 64 + kk * 32 + (lane >> 4) * 8);
                int rb = wc * 64 + i * 16 + (lane & 15);
                bfr[i] = *reinterpret_cast<const bf16x8*>(Bs + rb * 64 + kk * 32 + (lane >> 4) * 8);
            }
#pragma unroll
            for (int i = 0; i < 4; ++i)
#pragma unroll
                for (int j = 0; j < 4; ++j)
                    acc[i][j] = __builtin_amdgcn_mfma_f32_16x16x32_bf16(af[i], bfr[j], acc[i][j], 0, 0, 0);
        }
    }

    const int r4 = (lane >> 4) * 4;
    const int cl = lane & 15;
#pragma unroll
    for (int i = 0; i < 4; ++i) {
#pragma unroll
        for (int j = 0; j < 4; ++j) {
            size_t grow = m0 + wr * 64 + i * 16 + r4;
            size_t gcol = n0 + wc * 64 + j * 16 + cl;
            float bv = bias ? bias[gcol] : 0.f;
#pragma unroll
            for (int r = 0; r < 4; ++r)
                C[(grow + r) * (size_t)ldc + gcol] = acc[i][j][r] + bv;
        }
    }
}

// ---------------- 256x256 8-phase bf16 GEMM for the vocab projection ----------------
// M=65536, N=4096, K=640. 512 threads = 8 waves (2Mx4N), per-wave 128x64 out.
// T2 swizzle (linear gload_lds dest + pre-swizzled global src + swizzled ds_read).
// T4 counted vmcnt: issue order per tile = B0,B1,B2,B3,A0,A2,A1,A3 spread over
// phases; only vmcnt(2) waits (end-ph0 + boundary), never drain-to-0 mid-loop.
// Grid: XCD owns 2 n-tiles (B L2-resident); A-panel shared by the n-pair.
// C stored nontemporal (don't wash L2/LLC -> keep A/B reuse alive).
#define BK   64
#define BIGK 640
#define BIGN 4096
#define NT_  (BIGK / BK)

__global__ __launch_bounds__(512, 2) void gemm_big(const u16* __restrict__ A,
                                                   const u16* __restrict__ Bt,
                                                   float* __restrict__ C,
                                                   const float* __restrict__ bias) {
    __shared__ u16 lds[2][2][256 * BK];   // [buf][0=A,1=B]; 128 KiB

    const int tid = threadIdx.x;
    const int w = tid >> 6, lane = tid & 63;
    const int wr = w >> 2, wc = w & 3;
    const int fr = lane & 15, fq = lane >> 4;

    // XCD n-ownership: xcd = lin&7 owns n-tiles {2*xcd, 2*xcd+1}.
    // Within XCD: (mb, nsub) so the A-panel pair runs concurrently.
    const int lin = blockIdx.x;
    const int xcd = lin & 7;
    const int idx = lin >> 3;            // 0..511
    const size_t m0 = (size_t)(idx >> 1) * 256;
    const size_t n0 = (size_t)(xcd * 2 + (idx & 1)) * 256;

    // staging: chunk c = 64 rows of one operand; wave w stages rows c*64+w*8..+7.
    // LDS dest linear; global source col pre-swizzled (T2 involution).
    const int srow = lane >> 3;
    const int scol = ((lane & 7) * 16) ^ (srow << 4);
    const u16* agbase = A  + (m0 + w * 8 + srow) * (size_t)BIGK + (scol >> 1);
    const u16* bgbase = Bt + (n0 + w * 8 + srow) * (size_t)BIGK + (scol >> 1);
    const int ldst = (w * 8) * BK;

    f32x4 acc[8][4] = {};

#define STAGE_A(buf, c, k0)                                                        \
    __builtin_amdgcn_global_load_lds(                                              \
        (const __attribute__((address_space(1))) void*)(agbase + (size_t)(c) * 64 * BIGK + (k0)), \
        (__attribute__((address_space(3))) void*)(&lds[buf][0][(c) * 64 * BK + ldst]), 16, 0, 0)
#define STAGE_B(buf, c, k0)                                                        \
    __builtin_amdgcn_global_load_lds(                                              \
        (const __attribute__((address_space(1))) void*)(bgbase + (size_t)(c) * 64 * BIGK + (k0)), \
        (__attribute__((address_space(3))) void*)(&lds[buf][1][(c) * 64 * BK + ldst]), 16, 0, 0)

#define RD_A(buf, mh, mi, kk)                                                      \
    (*reinterpret_cast<const bf16x8*>(&lds[buf][0][                                \
        (wr * 128 + (mh) * 64 + (mi) * 16 + fr) * BK +                             \
        ((((kk) * 64 + fq * 16) ^ ((fr & 7) << 4)) >> 1)]))
#define RD_B(buf, ni, kk)                                                          \
    (*reinterpret_cast<const bf16x8*>(&lds[buf][1][                                \
        (wc * 64 + (ni) * 16 + fr) * BK +                                          \
        ((((kk) * 64 + fq * 16) ^ ((fr & 7) << 4)) >> 1)]))

#define WAIT2 asm volatile("s_waitcnt vmcnt(2)" ::: "memory")
#define WAIT0 asm volatile("s_waitcnt vmcnt(0)" ::: "memory")
#define LGKM0 asm volatile("s_waitcnt lgkmcnt(0)" ::: "memory")

    // prologue: tile 0, issue order B0..B3, A0, A2, A1, A3
    STAGE_B(0, 0, 0); STAGE_B(0, 1, 0); STAGE_B(0, 2, 0); STAGE_B(0, 3, 0);
    STAGE_A(0, 0, 0); STAGE_A(0, 2, 0); STAGE_A(0, 1, 0); STAGE_A(0, 3, 0);
    WAIT2;                                 // B*,A0,A2 resident; A1,A3 in flight
    __builtin_amdgcn_s_barrier();

    for (int t = 0; t < NT_; ++t) {
        const int cur = t & 1, nxt = cur ^ 1;
        const int kn = (t + 1) << 6;
        const bool pf = (t + 1 < NT_);
        bf16x8 af[4], b0[4], b1[4];

        // ---- phase 0: kk=0, m-low (reads B0-3 + A0/A2) ----
#pragma unroll
        for (int i = 0; i < 4; ++i) af[i] = RD_A(cur, 0, i, 0);
#pragma unroll
        for (int j = 0; j < 4; ++j) b0[j] = RD_B(cur, j, 0);
        if (pf) { STAGE_B(nxt, 0, kn); STAGE_B(nxt, 1, kn); }
        __builtin_amdgcn_s_barrier();
        LGKM0;
        __builtin_amdgcn_s_setprio(1);
#pragma unroll
        for (int i = 0; i < 4; ++i)
#pragma unroll
            for (int j = 0; j < 4; ++j)
                acc[i][j] = __builtin_amdgcn_mfma_f32_16x16x32_bf16(af[i], b0[j], acc[i][j], 0, 0, 0);
        __builtin_amdgcn_s_setprio(0);
        if (pf) WAIT2; else WAIT0;        // drain cur's A1,A3 (keep next B0,B1 in flight)
        __builtin_amdgcn_s_barrier();

        // ---- phase 1: kk=0, m-high (reads A1/A3) ----
#pragma unroll
        for (int i = 0; i < 4; ++i) af[i] = RD_A(cur, 1, i, 0);
        if (pf) { STAGE_B(nxt, 2, kn); STAGE_B(nxt, 3, kn); }
        __builtin_amdgcn_s_barrier();
        LGKM0;
        __builtin_amdgcn_s_setprio(1);
#pragma unroll
        for (int i = 0; i < 4; ++i)
#pragma unroll
            for (int j = 0; j < 4; ++j)
                acc[4 + i][j] = __builtin_amdgcn_mfma_f32_16x16x32_bf16(af[i], b0[j], acc[4 + i][j], 0, 0, 0);
        __builtin_amdgcn_s_setprio(0);
        __builtin_amdgcn_s_barrier();

        // ---- phase 2: kk=1, m-low (chunks already resident) ----
#pragma unroll
        for (int i = 0; i < 4; ++i) af[i] = RD_A(cur, 0, i, 1);
#pragma unroll
        for (int j = 0; j < 4; ++j) b1[j] = RD_B(cur, j, 1);
        if (pf) { STAGE_A(nxt, 0, kn); STAGE_A(nxt, 2, kn); }
        __builtin_amdgcn_s_barrier();
        LGKM0;
        __builtin_amdgcn_s_setprio(1);
#pragma unroll
        for (int i = 0; i < 4; ++i)
#pragma unroll
            for (int j = 0; j < 4; ++j)
                acc[i][j] = __builtin_amdgcn_mfma_f32_16x16x32_bf16(af[i], b1[j], acc[i][j], 0, 0, 0);
        __builtin_amdgcn_s_setprio(0);
        __builtin_amdgcn_s_barrier();

        // ---- phase 3: kk=1, m-high ----
#pragma unroll
        for (int i = 0; i < 4; ++i) af[i] = RD_A(cur, 1, i, 1);
        if (pf) { STAGE_A(nxt, 1, kn); STAGE_A(nxt, 3, kn); }
        __builtin_amdgcn_s_barrier();
        LGKM0;
        __builtin_amdgcn_s_setprio(1);
#pragma unroll
        for (int i = 0; i < 4; ++i)
#pragma unroll
            for (int j = 0; j < 4; ++j)
                acc[4 + i][j] = __builtin_amdgcn_mfma_f32_16x16x32_bf16(af[i], b1[j], acc[4 + i][j], 0, 0, 0);
        __builtin_amdgcn_s_setprio(0);
        if (pf) WAIT2;                    // next tile's B*,A0,A2 done; A1,A3 stay in flight
        __builtin_amdgcn_s_barrier();
    }

#undef STAGE_A
#undef STAGE_B
#undef RD_A
#undef RD_B
#undef WAIT2
#undef WAIT0
#undef LGKM0

    // epilogue: nontemporal stores (don't wash L2/LLC)
    const size_t crow0 = m0 + wr * 128 + fq * 4;
    const size_t ccol0 = n0 + wc * 64 + fr;
#pragma unroll
    for (int ni = 0; ni < 4; ++ni) {
        const size_t col = ccol0 + ni * 16;
        const float bv = bias[col];
#pragma unroll
        for (int mi = 0; mi < 8; ++mi) {
            const size_t rbase = crow0 + mi * 16;
#pragma unroll
            for (int r = 0; r < 4; ++r)
                __builtin_nontemporal_store(acc[mi][ni][r] + bv,
                                            &C[(rbase + r) * (size_t)BIGN + col]);
        }
    }
}

// ---------------- workspace layout (bytes) ----------------
static const size_t O_JOINT = 0;                              // bf16 [65536][640]
static const size_t O_WOUT  = 83886080;                       // bf16 [4096][640]
static const size_t O_ENCLN = 89128960;                       // bf16 [B*T][J]
static const size_t O_DECLN = 90439680;                       // bf16 [B*U][J]
static const size_t O_ENCIN = 90767360;                       // bf16 [T*B][EENC]
static const size_t O_DECIN = 92864512;                       // bf16 [U*B][EDEC]
static const size_t O_WENC  = 93192192;                       // bf16 [J][EENC]
static const size_t O_WDEC  = 94502912;                       // bf16 [J][EDEC]
static const size_t O_EPROJ = 95322112;                       // f32  [T*B][J]
static const size_t O_DPROJ = 97943552;                       // f32  [U*B][J]
static const size_t WS_NEEDED = 98598912;

extern "C" void kernel_launch(void* const* d_in, const int* in_sizes, int n_in,
                              void* d_out, int out_size, void* d_ws, size_t ws_size,
                              hipStream_t stream) {
    const float* enc   = (const float*)d_in[0];
    const float* dec   = (const float*)d_in[1];
    const float* Wenc  = (const float*)d_in[2];
    const float* benc  = (const float*)d_in[3];
    const float* genc  = (const float*)d_in[4];
    const float* beenc = (const float*)d_in[5];
    const float* Wdec  = (const float*)d_in[6];
    const float* bdec  = (const float*)d_in[7];
    const float* gdec  = (const float*)d_in[8];
    const float* bedec = (const float*)d_in[9];
    const float* Wout  = (const float*)d_in[10];
    const float* bout  = (const float*)d_in[11];
    float* out = (float*)d_out;

    if (ws_size < WS_NEEDED) return;

    char* ws = (char*)d_ws;
    u16* joint  = (u16*)(ws + O_JOINT);
    u16* wout_b = (u16*)(ws + O_WOUT);
    u16* encln  = (u16*)(ws + O_ENCLN);
    u16* decln  = (u16*)(ws + O_DECLN);
    u16* encin  = (u16*)(ws + O_ENCIN);
    u16* decin  = (u16*)(ws + O_DECIN);
    u16* wenc_b = (u16*)(ws + O_WENC);
    u16* wdec_b = (u16*)(ws + O_WDEC);
    float* eproj = (float*)(ws + O_EPROJ);
    float* dproj = (float*)(ws + O_DPROJ);

    // 1) bf16 converts
    cvt_bf16<<<1024, 256, 0, stream>>>(enc,  encin,  (T_ * B_ * EENC) / 4);
    cvt_bf16<<<160,  256, 0, stream>>>(dec,  decin,  (U_ * B_ * EDEC) / 4);
    cvt_bf16<<<640,  256, 0, stream>>>(Wenc, wenc_b, (J_ * EENC) / 4);
    cvt_bf16<<<400,  256, 0, stream>>>(Wdec, wdec_b, (J_ * EDEC) / 4);
    cvt_bf16<<<2560, 256, 0, stream>>>(Wout, wout_b, (V_ * J_) / 4);

    // 2) stage-1 projections (bias folded into LN)
    gemm_bt<<<dim3(J_ / 128, (T_ * B_) / 128), 256, 0, stream>>>(encin, wenc_b, eproj, nullptr, EENC, J_);
    gemm_bt<<<dim3(J_ / 128, (U_ * B_) / 128), 256, 0, stream>>>(decin, wdec_b, dproj, nullptr, EDEC, J_);

    // 3) LayerNorm (+bias +affine), transpose to [B, T/U, J], bf16
    ln_kernel<<<T_ * B_, 256, 0, stream>>>(eproj, benc, genc, beenc, encln, B_, T_);
    ln_kernel<<<U_ * B_, 256, 0, stream>>>(dproj, bdec, gdec, bedec, decln, B_, U_);

    // 4) joint = relu(enc + dec) materialized bf16 [B*T*U][J]
    joint_mat<<<(B_ * T_ * U_ * (J_ / 8)) / 256, 256, 0, stream>>>(encln, decln, joint);

    // 5) vocab projection: [65536, 640] x [640, 4096]^T + b_out -> d_out
    gemm_big<<<(B_ * T_ * U_ / 256) * (V_ / 256), 512, 0, stream>>>(joint, wout_b, out, bout);
}